// Round 9
// baseline (21531.717 us; speedup 1.0000x reference)
//
#include <hip/hip_runtime.h>
#include <stdint.h>

#define NBATCH  32
#define NPTS    131072
#define NPOINTS 4096
#define BPB     8            // blocks per batch -> grid = 256 = #CUs (co-resident by construction)
#define TPB     512          // threads per block
#define PPT     32           // points per thread = NPTS/BPB/TPB
#define PPB     (NPTS / BPB) // 16384

typedef unsigned long long u64;
typedef unsigned int u32;

// key layout: [60:49] = it+1 tag | [48:17] = f32 bits of max dist | [16:0] = 131071 - gi
// dist >= 0 -> float bits monotonic as unsigned; inverted index makes max() prefer
// the LOWEST global index on ties (jnp.argmax first-occurrence semantics).
//
// Distance = XLA->LLVM emitted form:
//   reduce: ((0+x^2)+y^2)+z^2 ; InstCombine folds fadd(0,x^2)->x^2 ;
//   DAGCombiner contracts fadd(mul,mul) on the FIRST operand:
//   d = fma(dz,dz, fma(dx,dx, dy*dy))   -- dy^2 separately rounded.
// (r5 tested the transposed inner fma(dy,dy,dx*dx): 1-ulp different value-set.)

__global__ __launch_bounds__(TPB, 2)
void fps_kernel(const float* __restrict__ inp, float* __restrict__ out,
                u64* __restrict__ slots)
{
#pragma clang fp contract(off)
    const int bid  = blockIdx.x;
    const int b    = bid & 31;   // batch
    const int j    = bid >> 5;   // block-within-batch 0..7
    const int t    = threadIdx.x;
    const int lane = t & 63;
    const int wid  = t >> 6;

    const float* P  = inp + (size_t)b * NPTS * 3;
    float* outP     = out + (size_t)b * NPOINTS * 3;
    float* outIdx   = out + (size_t)NBATCH * NPOINTS * 3 + (size_t)b * NPOINTS;

    const int base = j * PPB;

    // register-resident coords + running min-distance, all f32
    float px[PPT], py[PPT], pz[PPT], dist[PPT];
#pragma unroll
    for (int k = 0; k < PPT; ++k) {
        const int p = base + k * TPB + t;
        const float* pp = P + (size_t)p * 3;
        px[k] = pp[0]; py[k] = pp[1]; pz[k] = pp[2];
        dist[k] = 1e10f;
    }

    float qx = P[0], qy = P[1], qz = P[2];   // first selected index is 0

    if (j == 0 && t == 0) {
        outP[0] = qx; outP[1] = qy; outP[2] = qz;
        outIdx[0] = 0.0f;                    // whole d_out is read back as float32
    }

    u64* myslots = slots + (size_t)b * (2 * BPB * 2);

    __shared__ u64 skey[TPB / 64];
    __shared__ float sq[3];

    for (int it = 0; it < NPOINTS - 1; ++it) {
        // ---- update running min-distances, thread-local argmax (first-max kept) ----
        float m = -1.0f; int ki = 0;
#pragma unroll
        for (int k = 0; k < PPT; ++k) {
            float dx = px[k] - qx;
            float dy = py[k] - qy;
            float dz = pz[k] - qz;
            float yy = dy * dy;
            asm("" : "+v"(yy));                       // dy^2 stays a separately-rounded mul
            float d  = __builtin_fmaf(dz, dz,
                        __builtin_fmaf(dx, dx, yy));  // LLVM contraction shape
            float nd = fminf(dist[k], d);
            dist[k] = nd;
            if (nd > m) { m = nd; ki = k; }           // ascending k => ascending gi (first max)
        }
        const int gi = base + ki * TPB + t;
        u64 key = ((u64)__float_as_uint(m) << 17) | (u64)(131071 - gi);

        // ---- wave butterfly reduce (max key) ----
#pragma unroll
        for (int s = 1; s < 64; s <<= 1) {
            u64 o = __shfl_xor(key, s, 64);
            if (o > key) key = o;
        }
        if (lane == 0) skey[wid] = key;
        __syncthreads();

        if (wid == 0) {
            u64 k2 = (lane < TPB / 64) ? skey[lane] : 0ull;
#pragma unroll
            for (int s = 1; s < TPB / 64; s <<= 1) {
                u64 o = __shfl_xor(k2, s, 64);
                if (o > k2) k2 = o;
            }
            const int par = it & 1;
            const u64 tag = (u64)(it + 1) << 49;
            if (lane == 0) {
                __hip_atomic_store(&myslots[(par * BPB + j) * 2], tag | k2,
                                   __ATOMIC_RELEASE, __HIP_MEMORY_SCOPE_AGENT);
            }
            // ---- poll the BPB slots of this batch (self-validating barrier) ----
            u64 v = 0;
            bool ok = (lane >= BPB);
            int guard = 0;
            while (true) {
                if (!ok) {
                    v = __hip_atomic_load(&myslots[(par * BPB + lane) * 2 + 0],
                                          __ATOMIC_ACQUIRE, __HIP_MEMORY_SCOPE_AGENT);
                    ok = (v >> 49) >= (u64)(it + 1);
                }
                if (__all((int)ok)) break;
                if (++guard > (1 << 20)) break;   // hang safeguard (unreachable when co-resident)
            }
            u64 k3 = (lane < BPB) ? (v & ((1ull << 49) - 1)) : 0ull;
#pragma unroll
            for (int s = 1; s < BPB; s <<= 1) {
                u64 o = __shfl_xor(k3, s, 64);
                if (o > k3) k3 = o;
            }
            const int wgi = 131071 - (int)(k3 & 0x1FFFF);
            if (lane == 0) {
                const float* qp = P + (size_t)wgi * 3;
                float nqx = qp[0], nqy = qp[1], nqz = qp[2];
                sq[0] = nqx; sq[1] = nqy; sq[2] = nqz;
                if (j == 0) {
                    float* o3 = outP + (size_t)(it + 1) * 3;
                    o3[0] = nqx; o3[1] = nqy; o3[2] = nqz;
                    outIdx[it + 1] = (float)wgi;
                }
            }
        }
        __syncthreads();
        qx = sq[0]; qy = sq[1]; qz = sq[2];
    }
}

extern "C" void kernel_launch(void* const* d_in, const int* in_sizes, int n_in,
                              void* d_out, int out_size, void* d_ws, size_t ws_size,
                              hipStream_t stream)
{
    const float* inp = (const float*)d_in[0];
    float* outp      = (float*)d_out;
    u64* slots       = (u64*)d_ws;

    hipMemsetAsync(d_ws, 0, (size_t)NBATCH * 2 * BPB * 2 * sizeof(u64), stream);

    fps_kernel<<<NBATCH * BPB, TPB, 0, stream>>>(inp, outp, slots);
}

// Round 10
// 20290.831 us; speedup vs baseline: 1.0612x; 1.0612x over previous
//
#include <hip/hip_runtime.h>
#include <stdint.h>

#define NBATCH  32
#define NPTS    131072
#define NPOINTS 4096
#define BPB     8            // blocks per batch -> grid = 256 = #CUs (co-resident by construction)
#define TPB     512          // threads per block
#define PPT     32           // points per thread = NPTS/BPB/TPB
#define PPB     (NPTS / BPB) // 16384

typedef unsigned long long u64;
typedef unsigned int u32;

// key layout: [60:49] = it+1 tag | [48:17] = f32 bits of max dist | [16:0] = 131071 - gi
// dist >= 0 -> float bits monotonic as unsigned; inverted index makes max() prefer
// the LOWEST global index on ties (argmax first-occurrence semantics).
//
// Distance (matches harness reference bit-exactly, proven round 9):
//   d = fma(dz,dz, fma(dx,dx, dy*dy)) with dy^2 separately rounded.

__global__ __launch_bounds__(TPB, 2)
void fps_kernel(const float* __restrict__ inp, float* __restrict__ out,
                u64* __restrict__ slots)
{
#pragma clang fp contract(off)
    const int bid  = blockIdx.x;
    const int b    = bid & 31;   // batch
    const int j    = bid >> 5;   // block-within-batch 0..7
    const int t    = threadIdx.x;
    const int lane = t & 63;
    const int wid  = t >> 6;

    const float* P  = inp + (size_t)b * NPTS * 3;
    float* outP     = out + (size_t)b * NPOINTS * 3;
    float* outIdx   = out + (size_t)NBATCH * NPOINTS * 3 + (size_t)b * NPOINTS;

    const int base = j * PPB;

    // register-resident coords + running min-distance.
    // Each coord is laundered through inline asm: the value is then defined by
    // an asm op, which LLVM regalloc can neither rematerialize nor re-load from
    // global -> forces true register residency (round 9: compiler re-loaded all
    // 96 B/thread from L1/L2 every iteration, VGPR_Count=84).
    float px[PPT], py[PPT], pz[PPT], dist[PPT];
#pragma unroll
    for (int k = 0; k < PPT; ++k) {
        const int p = base + k * TPB + t;
        const float* pp = P + (size_t)p * 3;
        px[k] = pp[0]; py[k] = pp[1]; pz[k] = pp[2];
        asm("" : "+v"(px[k]), "+v"(py[k]), "+v"(pz[k]));   // pin in VGPRs
        dist[k] = 1e10f;
    }

    float qx = P[0], qy = P[1], qz = P[2];   // first selected index is 0

    if (j == 0 && t == 0) {
        outP[0] = qx; outP[1] = qy; outP[2] = qz;
        outIdx[0] = 0.0f;                    // whole d_out is read back as float32
    }

    u64* myslots = slots + (size_t)b * (2 * BPB * 2);

    __shared__ u64 skey[TPB / 64];
    __shared__ float sq[3];

    for (int it = 0; it < NPOINTS - 1; ++it) {
        // ---- update running min-distances, thread-local argmax (first-max kept) ----
        float m = -1.0f; int ki = 0;
#pragma unroll
        for (int k = 0; k < PPT; ++k) {
            float dx = px[k] - qx;
            float dy = py[k] - qy;
            float dz = pz[k] - qz;
            float yy = dy * dy;
            asm("" : "+v"(yy));                       // dy^2 stays a separately-rounded mul
            float d  = __builtin_fmaf(dz, dz,
                        __builtin_fmaf(dx, dx, yy));  // reference contraction shape
            float nd = fminf(dist[k], d);
            dist[k] = nd;
            if (nd > m) { m = nd; ki = k; }           // ascending k => ascending gi (first max)
        }
        const int gi = base + ki * TPB + t;
        u64 key = ((u64)__float_as_uint(m) << 17) | (u64)(131071 - gi);

        // ---- wave butterfly reduce (max key) ----
#pragma unroll
        for (int s = 1; s < 64; s <<= 1) {
            u64 o = __shfl_xor(key, s, 64);
            if (o > key) key = o;
        }
        if (lane == 0) skey[wid] = key;
        __syncthreads();

        if (wid == 0) {
            u64 k2 = (lane < TPB / 64) ? skey[lane] : 0ull;
#pragma unroll
            for (int s = 1; s < TPB / 64; s <<= 1) {
                u64 o = __shfl_xor(k2, s, 64);
                if (o > k2) k2 = o;
            }
            const int par = it & 1;
            const u64 tag = (u64)(it + 1) << 49;
            if (lane == 0) {
                __hip_atomic_store(&myslots[(par * BPB + j) * 2], tag | k2,
                                   __ATOMIC_RELEASE, __HIP_MEMORY_SCOPE_AGENT);
            }
            // ---- poll the BPB slots of this batch (self-validating barrier) ----
            u64 v = 0;
            bool ok = (lane >= BPB);
            int guard = 0;
            while (true) {
                if (!ok) {
                    v = __hip_atomic_load(&myslots[(par * BPB + lane) * 2 + 0],
                                          __ATOMIC_ACQUIRE, __HIP_MEMORY_SCOPE_AGENT);
                    ok = (v >> 49) >= (u64)(it + 1);
                }
                if (__all((int)ok)) break;
                if (++guard > (1 << 20)) break;   // hang safeguard (unreachable when co-resident)
            }
            u64 k3 = (lane < BPB) ? (v & ((1ull << 49) - 1)) : 0ull;
#pragma unroll
            for (int s = 1; s < BPB; s <<= 1) {
                u64 o = __shfl_xor(k3, s, 64);
                if (o > k3) k3 = o;
            }
            const int wgi = 131071 - (int)(k3 & 0x1FFFF);
            if (lane == 0) {
                const float* qp = P + (size_t)wgi * 3;
                float nqx = qp[0], nqy = qp[1], nqz = qp[2];
                sq[0] = nqx; sq[1] = nqy; sq[2] = nqz;
                if (j == 0) {
                    float* o3 = outP + (size_t)(it + 1) * 3;
                    o3[0] = nqx; o3[1] = nqy; o3[2] = nqz;
                    outIdx[it + 1] = (float)wgi;
                }
            }
        }
        __syncthreads();
        qx = sq[0]; qy = sq[1]; qz = sq[2];
    }
}

extern "C" void kernel_launch(void* const* d_in, const int* in_sizes, int n_in,
                              void* d_out, int out_size, void* d_ws, size_t ws_size,
                              hipStream_t stream)
{
    const float* inp = (const float*)d_in[0];
    float* outp      = (float*)d_out;
    u64* slots       = (u64*)d_ws;

    hipMemsetAsync(d_ws, 0, (size_t)NBATCH * 2 * BPB * 2 * sizeof(u64), stream);

    fps_kernel<<<NBATCH * BPB, TPB, 0, stream>>>(inp, outp, slots);
}

// Round 11
// 20143.353 us; speedup vs baseline: 1.0689x; 1.0073x over previous
//
#include <hip/hip_runtime.h>
#include <stdint.h>

#define NBATCH  32
#define NPTS    131072
#define NPOINTS 4096
#define BPB     8            // blocks per batch -> grid = 256 = #CUs (co-resident by construction)
#define TPB     512          // threads per block
#define PPT     32           // points per thread = NPTS/BPB/TPB
#define PPB     (NPTS / BPB) // 16384

typedef unsigned long long u64;
typedef unsigned int u32;

// key layout: [60:49] = it+1 tag | [48:17] = f32 bits of max dist | [16:0] = 131071 - gi
// dist >= 0 -> float bits monotonic as unsigned; inverted index makes max() prefer
// the LOWEST global index on ties (argmax first-occurrence semantics).
//
// Distance (matches harness reference bit-exactly, proven round 9):
//   d = fma(dz,dz, fma(dx,dx, dy*dy)) with dy^2 separately rounded.
//
// amdgpu_waves_per_eu(2,2): pin the scheduler's TARGET occupancy to 2 waves/EU
// (= our structural 1 block/CU). Round 10 evidence: with only a min bound, the
// scheduler aimed for ~6 waves/EU, shrank the kernel to 84 VGPRs by re-streaming
// the 384 B/thread coordinate set from L2/L3 every one of 4095 iterations
// (~50 MB/step chip-wide ~= 3.6 us/step), while actual occupancy stayed 1
// block/CU -- all cost, no benefit. With target=2, regalloc has a 256-VGPR
// budget and keeps the ~170-VGPR working set resident.

__global__ __attribute__((amdgpu_flat_work_group_size(TPB, TPB)))
           __attribute__((amdgpu_waves_per_eu(2, 2)))
void fps_kernel(const float* __restrict__ inp, float* __restrict__ out,
                u64* __restrict__ slots)
{
#pragma clang fp contract(off)
    const int bid  = blockIdx.x;
    const int b    = bid & 31;   // batch
    const int j    = bid >> 5;   // block-within-batch 0..7
    const int t    = threadIdx.x;
    const int lane = t & 63;
    const int wid  = t >> 6;

    const float* P  = inp + (size_t)b * NPTS * 3;
    float* outP     = out + (size_t)b * NPOINTS * 3;
    float* outIdx   = out + (size_t)NBATCH * NPOINTS * 3 + (size_t)b * NPOINTS;

    const int base = j * PPB;

    // register-resident coords + running min-distance (~170 VGPRs)
    float px[PPT], py[PPT], pz[PPT], dist[PPT];
#pragma unroll
    for (int k = 0; k < PPT; ++k) {
        const int p = base + k * TPB + t;
        const float* pp = P + (size_t)p * 3;
        px[k] = pp[0]; py[k] = pp[1]; pz[k] = pp[2];
        asm("" : "+v"(px[k]), "+v"(py[k]), "+v"(pz[k]));   // belt-and-braces pin
        dist[k] = 1e10f;
    }

    float qx = P[0], qy = P[1], qz = P[2];   // first selected index is 0

    if (j == 0 && t == 0) {
        outP[0] = qx; outP[1] = qy; outP[2] = qz;
        outIdx[0] = 0.0f;                    // whole d_out is read back as float32
    }

    u64* myslots = slots + (size_t)b * (2 * BPB * 2);

    __shared__ u64 skey[TPB / 64];
    __shared__ float sq[3];

    for (int it = 0; it < NPOINTS - 1; ++it) {
        // ---- update running min-distances, thread-local argmax (first-max kept) ----
        float m = -1.0f; int ki = 0;
#pragma unroll
        for (int k = 0; k < PPT; ++k) {
            float dx = px[k] - qx;
            float dy = py[k] - qy;
            float dz = pz[k] - qz;
            float yy = dy * dy;
            asm("" : "+v"(yy));                       // dy^2 stays a separately-rounded mul
            float d  = __builtin_fmaf(dz, dz,
                        __builtin_fmaf(dx, dx, yy));  // reference contraction shape
            float nd = fminf(dist[k], d);
            dist[k] = nd;
            if (nd > m) { m = nd; ki = k; }           // ascending k => ascending gi (first max)
        }
        const int gi = base + ki * TPB + t;
        u64 key = ((u64)__float_as_uint(m) << 17) | (u64)(131071 - gi);

        // ---- wave butterfly reduce (max key) ----
#pragma unroll
        for (int s = 1; s < 64; s <<= 1) {
            u64 o = __shfl_xor(key, s, 64);
            if (o > key) key = o;
        }
        if (lane == 0) skey[wid] = key;
        __syncthreads();

        if (wid == 0) {
            u64 k2 = (lane < TPB / 64) ? skey[lane] : 0ull;
#pragma unroll
            for (int s = 1; s < TPB / 64; s <<= 1) {
                u64 o = __shfl_xor(k2, s, 64);
                if (o > k2) k2 = o;
            }
            const int par = it & 1;
            const u64 tag = (u64)(it + 1) << 49;
            if (lane == 0) {
                __hip_atomic_store(&myslots[(par * BPB + j) * 2], tag | k2,
                                   __ATOMIC_RELEASE, __HIP_MEMORY_SCOPE_AGENT);
            }
            // ---- poll the BPB slots of this batch (self-validating barrier) ----
            u64 v = 0;
            bool ok = (lane >= BPB);
            int guard = 0;
            while (true) {
                if (!ok) {
                    v = __hip_atomic_load(&myslots[(par * BPB + lane) * 2 + 0],
                                          __ATOMIC_ACQUIRE, __HIP_MEMORY_SCOPE_AGENT);
                    ok = (v >> 49) >= (u64)(it + 1);
                }
                if (__all((int)ok)) break;
                if (++guard > (1 << 20)) break;   // hang safeguard (unreachable when co-resident)
            }
            u64 k3 = (lane < BPB) ? (v & ((1ull << 49) - 1)) : 0ull;
#pragma unroll
            for (int s = 1; s < BPB; s <<= 1) {
                u64 o = __shfl_xor(k3, s, 64);
                if (o > k3) k3 = o;
            }
            const int wgi = 131071 - (int)(k3 & 0x1FFFF);
            if (lane == 0) {
                const float* qp = P + (size_t)wgi * 3;
                float nqx = qp[0], nqy = qp[1], nqz = qp[2];
                sq[0] = nqx; sq[1] = nqy; sq[2] = nqz;
                if (j == 0) {
                    float* o3 = outP + (size_t)(it + 1) * 3;
                    o3[0] = nqx; o3[1] = nqy; o3[2] = nqz;
                    outIdx[it + 1] = (float)wgi;
                }
            }
        }
        __syncthreads();
        qx = sq[0]; qy = sq[1]; qz = sq[2];
    }
}

extern "C" void kernel_launch(void* const* d_in, const int* in_sizes, int n_in,
                              void* d_out, int out_size, void* d_ws, size_t ws_size,
                              hipStream_t stream)
{
    const float* inp = (const float*)d_in[0];
    float* outp      = (float*)d_out;
    u64* slots       = (u64*)d_ws;

    hipMemsetAsync(d_ws, 0, (size_t)NBATCH * 2 * BPB * 2 * sizeof(u64), stream);

    fps_kernel<<<NBATCH * BPB, TPB, 0, stream>>>(inp, outp, slots);
}

// Round 12
// 19882.623 us; speedup vs baseline: 1.0829x; 1.0131x over previous
//
#include <hip/hip_runtime.h>
#include <stdint.h>

#define NBATCH  32
#define NPTS    131072
#define NPOINTS 4096
#define BPB     8            // blocks per batch -> grid = 256 = #CUs (co-resident by construction)
#define TPB     512          // threads per block
#define PPT     32           // points per thread = NPTS/BPB/TPB
#define PPB     (NPTS / BPB) // 16384

typedef unsigned long long u64;
typedef unsigned int u32;

// key layout: [60:49] = it+1 tag | [48:17] = f32 bits of max dist | [16:0] = 131071 - gi
// dist >= 0 -> float bits monotonic as unsigned; inverted index makes max() prefer
// the LOWEST global index on ties (argmax first-occurrence semantics).
//
// Distance (matches harness reference bit-exactly, proven round 9):
//   d = fma(dz,dz, fma(dx,dx, dy*dy)) with dy^2 separately rounded.
//
// Register-residency enforcement history:
//   r9:  plain loads            -> compiler sank coord loads into the loop (VGPR 84)
//   r10: non-volatile asm pin   -> sinkable (load+no-op asm legally re-executed) -> no change
//   r11: waves_per_eu(2,2)      -> budget raised but loads still sunk (VGPR 92)
//   r12: asm VOLATILE pin       -> cannot be sunk/duplicated/remat'd; values must
//        stay live across the loop; 256-VGPR budget makes VGPR the only sane home.

__global__ __attribute__((amdgpu_flat_work_group_size(TPB, TPB)))
           __attribute__((amdgpu_waves_per_eu(2, 2)))
void fps_kernel(const float* __restrict__ inp, float* __restrict__ out,
                u64* __restrict__ slots)
{
#pragma clang fp contract(off)
    const int bid  = blockIdx.x;
    const int b    = bid & 31;   // batch
    const int j    = bid >> 5;   // block-within-batch 0..7
    const int t    = threadIdx.x;
    const int lane = t & 63;
    const int wid  = t >> 6;

    const float* P  = inp + (size_t)b * NPTS * 3;
    float* outP     = out + (size_t)b * NPOINTS * 3;
    float* outIdx   = out + (size_t)NBATCH * NPOINTS * 3 + (size_t)b * NPOINTS;

    const int base = j * PPB;

    // register-resident coords + running min-distance (~170 VGPRs)
    float px[PPT], py[PPT], pz[PPT], dist[PPT];
#pragma unroll
    for (int k = 0; k < PPT; ++k) {
        const int p = base + k * TPB + t;
        const float* pp = P + (size_t)p * 3;
        px[k] = pp[0]; py[k] = pp[1]; pz[k] = pp[2];
        // VOLATILE pin: must execute exactly once -> load cannot be sunk into
        // the it-loop; value is forced live in a VGPR for the whole kernel.
        asm volatile("" : "+v"(px[k]), "+v"(py[k]), "+v"(pz[k]));
        dist[k] = 1e10f;
    }

    float qx = P[0], qy = P[1], qz = P[2];   // first selected index is 0

    if (j == 0 && t == 0) {
        outP[0] = qx; outP[1] = qy; outP[2] = qz;
        outIdx[0] = 0.0f;                    // whole d_out is read back as float32
    }

    u64* myslots = slots + (size_t)b * (2 * BPB * 2);

    __shared__ u64 skey[TPB / 64];
    __shared__ float sq[3];

    for (int it = 0; it < NPOINTS - 1; ++it) {
        // ---- update running min-distances, thread-local argmax (first-max kept) ----
        float m = -1.0f; int ki = 0;
#pragma unroll
        for (int k = 0; k < PPT; ++k) {
            float dx = px[k] - qx;
            float dy = py[k] - qy;
            float dz = pz[k] - qz;
            float yy = dy * dy;
            asm("" : "+v"(yy));                       // dy^2 stays a separately-rounded mul
            float d  = __builtin_fmaf(dz, dz,
                        __builtin_fmaf(dx, dx, yy));  // reference contraction shape
            float nd = fminf(dist[k], d);
            dist[k] = nd;
            if (nd > m) { m = nd; ki = k; }           // ascending k => ascending gi (first max)
        }
        const int gi = base + ki * TPB + t;
        u64 key = ((u64)__float_as_uint(m) << 17) | (u64)(131071 - gi);

        // ---- wave butterfly reduce (max key) ----
#pragma unroll
        for (int s = 1; s < 64; s <<= 1) {
            u64 o = __shfl_xor(key, s, 64);
            if (o > key) key = o;
        }
        if (lane == 0) skey[wid] = key;
        __syncthreads();

        if (wid == 0) {
            u64 k2 = (lane < TPB / 64) ? skey[lane] : 0ull;
#pragma unroll
            for (int s = 1; s < TPB / 64; s <<= 1) {
                u64 o = __shfl_xor(k2, s, 64);
                if (o > k2) k2 = o;
            }
            const int par = it & 1;
            const u64 tag = (u64)(it + 1) << 49;
            if (lane == 0) {
                __hip_atomic_store(&myslots[(par * BPB + j) * 2], tag | k2,
                                   __ATOMIC_RELEASE, __HIP_MEMORY_SCOPE_AGENT);
            }
            // ---- poll the BPB slots of this batch (self-validating barrier) ----
            u64 v = 0;
            bool ok = (lane >= BPB);
            int guard = 0;
            while (true) {
                if (!ok) {
                    v = __hip_atomic_load(&myslots[(par * BPB + lane) * 2 + 0],
                                          __ATOMIC_ACQUIRE, __HIP_MEMORY_SCOPE_AGENT);
                    ok = (v >> 49) >= (u64)(it + 1);
                }
                if (__all((int)ok)) break;
                if (++guard > (1 << 20)) break;   // hang safeguard (unreachable when co-resident)
            }
            u64 k3 = (lane < BPB) ? (v & ((1ull << 49) - 1)) : 0ull;
#pragma unroll
            for (int s = 1; s < BPB; s <<= 1) {
                u64 o = __shfl_xor(k3, s, 64);
                if (o > k3) k3 = o;
            }
            const int wgi = 131071 - (int)(k3 & 0x1FFFF);
            if (lane == 0) {
                const float* qp = P + (size_t)wgi * 3;
                float nqx = qp[0], nqy = qp[1], nqz = qp[2];
                sq[0] = nqx; sq[1] = nqy; sq[2] = nqz;
                if (j == 0) {
                    float* o3 = outP + (size_t)(it + 1) * 3;
                    o3[0] = nqx; o3[1] = nqy; o3[2] = nqz;
                    outIdx[it + 1] = (float)wgi;
                }
            }
        }
        __syncthreads();
        qx = sq[0]; qy = sq[1]; qz = sq[2];
    }
}

extern "C" void kernel_launch(void* const* d_in, const int* in_sizes, int n_in,
                              void* d_out, int out_size, void* d_ws, size_t ws_size,
                              hipStream_t stream)
{
    const float* inp = (const float*)d_in[0];
    float* outp      = (float*)d_out;
    u64* slots       = (u64*)d_ws;

    hipMemsetAsync(d_ws, 0, (size_t)NBATCH * 2 * BPB * 2 * sizeof(u64), stream);

    fps_kernel<<<NBATCH * BPB, TPB, 0, stream>>>(inp, outp, slots);
}